// Round 2
// baseline (2897.325 us; speedup 1.0000x reference)
//
#include <hip/hip_runtime.h>

static constexpr int NNODES = 1000000;
static constexpr int NEDGES = 16000000;

// ---------- degree / normalization ----------

__global__ void k_init_deg(float* __restrict__ deg) {
    int i = blockIdx.x * blockDim.x + threadIdx.x;
    if (i < NNODES) deg[i] = 1.0f;  // self-loop contributes 1 to every node
}

__global__ void k_count_deg(const int* __restrict__ col,
                            float* __restrict__ deg) {
    long long stride = (long long)gridDim.x * blockDim.x;
    for (long long e = (long long)blockIdx.x * blockDim.x + threadIdx.x;
         e < NEDGES; e += stride) {
        atomicAdd(&deg[col[e]], 1.0f);
    }
}

__global__ void k_rsqrt_inplace(float* __restrict__ deg) {
    int i = blockIdx.x * blockDim.x + threadIdx.x;
    if (i < NNODES) deg[i] = rsqrtf(deg[i]);  // deg >= 1 always (self-loops)
}

// ---------- layer 1 linear: h1 = x @ W1 ; agg1 = h1 * dis^2 (self-loop term) ----------

__global__ void k_lin1(const float* __restrict__ x, const float* __restrict__ W1,
                       const float* __restrict__ dis,
                       float* __restrict__ h1, float* __restrict__ agg1) {
    __shared__ float w[144];  // 9x16
    if (threadIdx.x < 144) w[threadIdx.x] = W1[threadIdx.x];
    __syncthreads();
    int i = blockIdx.x * blockDim.x + threadIdx.x;
    if (i >= NNODES) return;
    float xv[9];
#pragma unroll
    for (int k = 0; k < 9; ++k) xv[k] = x[(long long)i * 9 + k];
    float d = dis[i];
    float d2 = d * d;
#pragma unroll
    for (int j = 0; j < 16; ++j) {
        float acc = 0.f;
#pragma unroll
        for (int k = 0; k < 9; ++k) acc = fmaf(xv[k], w[k * 16 + j], acc);
        h1[(long long)i * 16 + j] = acc;
        agg1[(long long)i * 16 + j] = acc * d2;
    }
}

// ---------- edge aggregation: agg[col] += h[row] * dis[row]*dis[col] ----------
// 16 lanes per edge; for F<16 the high lanes are masked off.

template <int F>
__global__ void k_edge(const int* __restrict__ row, const int* __restrict__ col,
                       const float* __restrict__ dis,
                       const float* __restrict__ h, float* __restrict__ agg) {
    const long long total = (long long)NEDGES * 16;
    const long long stride = (long long)gridDim.x * blockDim.x;
    for (long long t = (long long)blockIdx.x * blockDim.x + threadIdx.x;
         t < total; t += stride) {
        int e = (int)(t >> 4);
        int j = (int)(t & 15);
        if (F == 16 || j < F) {
            int r = row[e];
            int c = col[e];
            float nrm = dis[r] * dis[c];
            atomicAdd(&agg[(long long)c * F + j], h[(long long)r * F + j] * nrm);
        }
    }
}

// ---------- layer 2 linear: hin = relu(agg1 + b1); h2 = hin @ W2 ; agg2 = h2*dis^2 ----------

__global__ void k_lin2(const float* __restrict__ agg1, const float* __restrict__ b1,
                       const float* __restrict__ W2, const float* __restrict__ dis,
                       float* __restrict__ h2, float* __restrict__ agg2) {
    __shared__ float w[160];  // 16x10
    __shared__ float bb[16];
    if (threadIdx.x < 160) w[threadIdx.x] = W2[threadIdx.x];
    if (threadIdx.x < 16) bb[threadIdx.x] = b1[threadIdx.x];
    __syncthreads();
    int i = blockIdx.x * blockDim.x + threadIdx.x;
    if (i >= NNODES) return;
    float hv[16];
#pragma unroll
    for (int k = 0; k < 16; ++k)
        hv[k] = fmaxf(agg1[(long long)i * 16 + k] + bb[k], 0.f);
    float d = dis[i];
    float d2 = d * d;
#pragma unroll
    for (int j = 0; j < 10; ++j) {
        float acc = 0.f;
#pragma unroll
        for (int k = 0; k < 16; ++k) acc = fmaf(hv[k], w[k * 10 + j], acc);
        h2[(long long)i * 10 + j] = acc;
        agg2[(long long)i * 10 + j] = acc * d2;
    }
}

// ---------- final: out = (agg2 + b2) @ Wf + bf ----------

__global__ void k_final(const float* __restrict__ agg2, const float* __restrict__ b2,
                        const float* __restrict__ Wf, const float* __restrict__ bf,
                        float* __restrict__ out) {
    __shared__ float w[10];
    __shared__ float bb[10];
    __shared__ float bfv;
    if (threadIdx.x < 10) { w[threadIdx.x] = Wf[threadIdx.x]; bb[threadIdx.x] = b2[threadIdx.x]; }
    if (threadIdx.x == 0) bfv = bf[0];
    __syncthreads();
    int i = blockIdx.x * blockDim.x + threadIdx.x;
    if (i >= NNODES) return;
    float acc = bfv;
#pragma unroll
    for (int j = 0; j < 10; ++j)
        acc = fmaf(agg2[(long long)i * 10 + j] + bb[j], w[j], acc);
    out[i] = acc;
}

extern "C" void kernel_launch(void* const* d_in, const int* in_sizes, int n_in,
                              void* d_out, int out_size, void* d_ws, size_t ws_size,
                              hipStream_t stream) {
    const float* x   = (const float*)d_in[0];
    const int*   ei  = (const int*)d_in[1];   // int64 in ref, int32 on device per harness
    const float* W1  = (const float*)d_in[2];
    const float* b1  = (const float*)d_in[3];
    const float* W2  = (const float*)d_in[4];
    const float* b2  = (const float*)d_in[5];
    const float* Wf  = (const float*)d_in[6];
    const float* bf  = (const float*)d_in[7];
    float* out = (float*)d_out;

    const int* row = ei;            // edge_index[0]
    const int* col = ei + NEDGES;   // edge_index[1]

    char* ws = (char*)d_ws;
    size_t off = 0;
    auto alloc = [&](size_t bytes) -> void* {
        void* p = ws + off;
        off += (bytes + 255) & ~255ULL;
        return p;
    };
    float* deg  = (float*)alloc((size_t)NNODES * 4);       // becomes dis in place
    float* h1   = (float*)alloc((size_t)NNODES * 16 * 4);  // reused as agg2 later
    float* agg1 = (float*)alloc((size_t)NNODES * 16 * 4);
    float* h2   = (float*)alloc((size_t)NNODES * 10 * 4);
    float* agg2 = h1;  // h1 dead after edge pass 1

    const int TB = 256;
    const int nodeGrid = (NNODES + TB - 1) / TB;
    const int edgeGrid = 8192;

    k_init_deg<<<nodeGrid, TB, 0, stream>>>(deg);
    k_count_deg<<<edgeGrid, TB, 0, stream>>>(col, deg);
    k_rsqrt_inplace<<<nodeGrid, TB, 0, stream>>>(deg);
    float* dis = deg;

    k_lin1<<<nodeGrid, TB, 0, stream>>>(x, W1, dis, h1, agg1);
    k_edge<16><<<edgeGrid, TB, 0, stream>>>(row, col, dis, h1, agg1);
    k_lin2<<<nodeGrid, TB, 0, stream>>>(agg1, b1, W2, dis, h2, agg2);
    k_edge<10><<<edgeGrid, TB, 0, stream>>>(row, col, dis, h2, agg2);
    k_final<<<nodeGrid, TB, 0, stream>>>(agg2, b2, Wf, bf, out);
}

// Round 3
// 2415.094 us; speedup vs baseline: 1.1997x; 1.1997x over previous
//
#include <hip/hip_runtime.h>

static constexpr int NN = 1000000;
static constexpr int NE = 16000000;
static constexpr int PAD = 16;            // feature stride for gather arrays

static constexpr int SCAN_BLK = 1024;     // elements per scan block
static constexpr int SCAN_THREADS = 256;  // 4 elements / thread
static constexpr int NSCAN = (NN + SCAN_BLK - 1) / SCAN_BLK;  // 977

// ---------- build: degree histogram ----------

__global__ void k_zero_int(int* __restrict__ p, int n) {
    int i = blockIdx.x * blockDim.x + threadIdx.x;
    if (i < n) p[i] = 0;
}

__global__ void k_hist(const int* __restrict__ col, int* __restrict__ deg) {
    long long stride = (long long)gridDim.x * blockDim.x;
    for (long long e = (long long)blockIdx.x * blockDim.x + threadIdx.x;
         e < NE; e += stride)
        atomicAdd(&deg[col[e]], 1);
}

// ---------- build: exclusive scan of deg -> ptr ----------

__global__ void k_block_sums(const int* __restrict__ deg, int* __restrict__ bsums) {
    __shared__ int sm[SCAN_THREADS];
    int t = threadIdx.x;
    int base = blockIdx.x * SCAN_BLK + t * 4;
    int s = 0;
#pragma unroll
    for (int k = 0; k < 4; ++k) {
        int idx = base + k;
        if (idx < NN) s += deg[idx];
    }
    sm[t] = s;
    __syncthreads();
    for (int off = SCAN_THREADS / 2; off > 0; off >>= 1) {
        if (t < off) sm[t] += sm[t + off];
        __syncthreads();
    }
    if (t == 0) bsums[blockIdx.x] = sm[0];
}

__global__ void k_scan_bsums(int* __restrict__ bsums, int n) {  // one block, 1024 thr
    __shared__ int sm[1024];
    int t = threadIdx.x;
    sm[t] = (t < n) ? bsums[t] : 0;
    __syncthreads();
    for (int off = 1; off < 1024; off <<= 1) {
        int x = (t >= off) ? sm[t - off] : 0;
        __syncthreads();
        sm[t] += x;
        __syncthreads();
    }
    if (t < n) bsums[t] = (t == 0) ? 0 : sm[t - 1];  // exclusive
}

__global__ void k_scan_final(const int* __restrict__ deg, const int* __restrict__ boff,
                             int* __restrict__ ptr) {
    __shared__ int sm[SCAN_THREADS];
    int t = threadIdx.x;
    int base = blockIdx.x * SCAN_BLK + t * 4;
    int s = 0;
#pragma unroll
    for (int k = 0; k < 4; ++k) {
        int idx = base + k;
        if (idx < NN) s += deg[idx];
    }
    sm[t] = s;
    __syncthreads();
    for (int off = 1; off < SCAN_THREADS; off <<= 1) {
        int x = (t >= off) ? sm[t - off] : 0;
        __syncthreads();
        sm[t] += x;
        __syncthreads();
    }
    int running = boff[blockIdx.x] + ((t == 0) ? 0 : sm[t - 1]);
#pragma unroll
    for (int k = 0; k < 4; ++k) {
        int idx = base + k;
        if (idx < NN) { ptr[idx] = running; running += deg[idx]; }
    }
    if (blockIdx.x == 0 && t == 0) ptr[NN] = NE;
}

// ---------- build: dis = rsqrt(deg+1); cursor = ptr ----------

__global__ void k_dis(const int* __restrict__ deg, float* __restrict__ dis) {
    int i = blockIdx.x * blockDim.x + threadIdx.x;
    if (i < NN) dis[i] = rsqrtf((float)(deg[i] + 1));  // +1 self-loop
}

__global__ void k_copy_int(const int* __restrict__ src, int* __restrict__ dst, int n) {
    int i = blockIdx.x * blockDim.x + threadIdx.x;
    if (i < n) dst[i] = src[i];
}

__global__ void k_scatter(const int* __restrict__ row, const int* __restrict__ col,
                          int* __restrict__ cursor, int* __restrict__ sortedRow) {
    long long stride = (long long)gridDim.x * blockDim.x;
    for (long long e = (long long)blockIdx.x * blockDim.x + threadIdx.x;
         e < NE; e += stride) {
        int c = col[e];
        int pos = atomicAdd(&cursor[c], 1);
        sortedRow[pos] = row[e];
    }
}

// ---------- layer 1 linear: g1 = (x @ W1) * dis  (stride PAD) ----------

__global__ void k_lin1(const float* __restrict__ x, const float* __restrict__ W1,
                       const float* __restrict__ dis, float* __restrict__ g1) {
    __shared__ float w[144];  // 9x16
    if (threadIdx.x < 144) w[threadIdx.x] = W1[threadIdx.x];
    __syncthreads();
    int i = blockIdx.x * blockDim.x + threadIdx.x;
    if (i >= NN) return;
    float xv[9];
#pragma unroll
    for (int k = 0; k < 9; ++k) xv[k] = x[(long long)i * 9 + k];
    float d = dis[i];
#pragma unroll
    for (int j = 0; j < 16; ++j) {
        float acc = 0.f;
#pragma unroll
        for (int k = 0; k < 9; ++k) acc = fmaf(xv[k], w[k * 16 + j], acc);
        g1[(long long)i * PAD + j] = acc * d;
    }
}

// ---------- pull aggregation: agg[n] = dis[n] * (g[n] + sum_{r in in(n)} g[r]) ----------
// 16 lanes per node, 4 nodes per wave, 16 nodes per 256-thread block.

template <int F, int AGG_STRIDE>
__global__ void k_pull(const int* __restrict__ ptr, const int* __restrict__ sortedRow,
                       const float* __restrict__ dis, const float* __restrict__ g,
                       float* __restrict__ agg) {
    int grp = threadIdx.x >> 4;
    int j = threadIdx.x & 15;
    int n = blockIdx.x * 16 + grp;
    if (n >= NN) return;
    float acc = 0.f;
    if (j < F) acc = g[(long long)n * PAD + j];  // self-loop term
    int e0 = ptr[n], e1 = ptr[n + 1];
    for (int e = e0; e < e1; ++e) {
        int r = sortedRow[e];  // 16-lane broadcast
        if (j < F) acc += g[(long long)r * PAD + j];
    }
    if (j < F) agg[(long long)n * AGG_STRIDE + j] = dis[n] * acc;
}

// ---------- layer 2 linear (in-place): g2 = relu(agg1+b1) @ W2 * dis ----------

__global__ void k_lin2(float* __restrict__ agg1g2, const float* __restrict__ b1,
                       const float* __restrict__ W2, const float* __restrict__ dis) {
    __shared__ float w[160];  // 16x10
    __shared__ float bb[16];
    if (threadIdx.x < 160) w[threadIdx.x] = W2[threadIdx.x];
    if (threadIdx.x < 16) bb[threadIdx.x] = b1[threadIdx.x];
    __syncthreads();
    int i = blockIdx.x * blockDim.x + threadIdx.x;
    if (i >= NN) return;
    float hv[16];
#pragma unroll
    for (int k = 0; k < 16; ++k)
        hv[k] = fmaxf(agg1g2[(long long)i * PAD + k] + bb[k], 0.f);
    float d = dis[i];
#pragma unroll
    for (int j = 0; j < 10; ++j) {
        float acc = 0.f;
#pragma unroll
        for (int k = 0; k < 16; ++k) acc = fmaf(hv[k], w[k * 10 + j], acc);
        agg1g2[(long long)i * PAD + j] = acc * d;  // in-place: read-all-then-write
    }
}

// ---------- final: out = (agg2 + b2) @ Wf + bf ----------

__global__ void k_final(const float* __restrict__ agg2, const float* __restrict__ b2,
                        const float* __restrict__ Wf, const float* __restrict__ bf,
                        float* __restrict__ out) {
    __shared__ float w[10];
    __shared__ float bb[10];
    __shared__ float bfv;
    if (threadIdx.x < 10) { w[threadIdx.x] = Wf[threadIdx.x]; bb[threadIdx.x] = b2[threadIdx.x]; }
    if (threadIdx.x == 0) bfv = bf[0];
    __syncthreads();
    int i = blockIdx.x * blockDim.x + threadIdx.x;
    if (i >= NN) return;
    float acc = bfv;
#pragma unroll
    for (int j = 0; j < 10; ++j)
        acc = fmaf(agg2[(long long)i * 10 + j] + bb[j], w[j], acc);
    out[i] = acc;
}

extern "C" void kernel_launch(void* const* d_in, const int* in_sizes, int n_in,
                              void* d_out, int out_size, void* d_ws, size_t ws_size,
                              hipStream_t stream) {
    const float* x  = (const float*)d_in[0];
    const int*   ei = (const int*)d_in[1];
    const float* W1 = (const float*)d_in[2];
    const float* b1 = (const float*)d_in[3];
    const float* W2 = (const float*)d_in[4];
    const float* b2 = (const float*)d_in[5];
    const float* Wf = (const float*)d_in[6];
    const float* bf = (const float*)d_in[7];
    float* out = (float*)d_out;

    const int* row = ei;
    const int* col = ei + NE;

    char* ws = (char*)d_ws;
    size_t off = 0;
    auto alloc = [&](size_t bytes) -> void* {
        void* p = ws + off;
        off += (bytes + 255) & ~255ULL;
        return p;
    };
    int*   deg       = (int*)  alloc((size_t)NN * 4);
    int*   ptr       = (int*)  alloc((size_t)(NN + 1) * 4);
    float* dis       = (float*)alloc((size_t)NN * 4);
    int*   cursor    = (int*)  alloc((size_t)NN * 4);
    int*   bsums     = (int*)  alloc((size_t)NSCAN * 4);
    int*   sortedRow = (int*)  alloc((size_t)NE * 4);
    float* g1        = (float*)alloc((size_t)NN * PAD * 4);  // reused as agg2
    float* agg1      = (float*)alloc((size_t)NN * PAD * 4);  // reused in-place as g2
    float* agg2      = g1;  // g1 dead after pull1

    const int TB = 256;
    const int nodeGrid = (NN + TB - 1) / TB;
    const int pullGrid = (NN + 15) / 16;
    const int edgeGrid = 8192;

    k_zero_int<<<nodeGrid, TB, 0, stream>>>(deg, NN);
    k_hist<<<edgeGrid, TB, 0, stream>>>(col, deg);
    k_block_sums<<<NSCAN, SCAN_THREADS, 0, stream>>>(deg, bsums);
    k_scan_bsums<<<1, 1024, 0, stream>>>(bsums, NSCAN);
    k_scan_final<<<NSCAN, SCAN_THREADS, 0, stream>>>(deg, bsums, ptr);
    k_dis<<<nodeGrid, TB, 0, stream>>>(deg, dis);
    k_copy_int<<<nodeGrid, TB, 0, stream>>>(ptr, cursor, NN);
    k_scatter<<<edgeGrid, TB, 0, stream>>>(row, col, cursor, sortedRow);

    k_lin1<<<nodeGrid, TB, 0, stream>>>(x, W1, dis, g1);
    k_pull<16, PAD><<<pullGrid, TB, 0, stream>>>(ptr, sortedRow, dis, g1, agg1);
    k_lin2<<<nodeGrid, TB, 0, stream>>>(agg1, b1, W2, dis);  // agg1 -> g2 in place
    k_pull<10, 10><<<pullGrid, TB, 0, stream>>>(ptr, sortedRow, dis, agg1, agg2);
    k_final<<<nodeGrid, TB, 0, stream>>>(agg2, b2, Wf, bf, out);
}

// Round 4
// 1628.012 us; speedup vs baseline: 1.7797x; 1.4835x over previous
//
#include <hip/hip_runtime.h>

static constexpr int NN = 1000000;
static constexpr int NE = 16000000;
static constexpr int PAD = 16;                 // feature stride for gather arrays
static constexpr int NB = (NN + 1023) >> 10;   // 977 buckets of 1024 nodes
static constexpr int NWG_BIN = 512;
static constexpr int EPW = NE / NWG_BIN;       // 31250 edges per binning workgroup

static constexpr int SCAN_BLK = 1024;
static constexpr int SCAN_THREADS = 256;
static constexpr int NSCAN = (NN + SCAN_BLK - 1) / SCAN_BLK;  // 977

// ---------- build step 1: per-bucket edge counts (LDS histogram) ----------

__global__ void k_bincount(const int* __restrict__ col, int* __restrict__ bucketCount) {
    __shared__ int cnt[NB];
    for (int i = threadIdx.x; i < NB; i += blockDim.x) cnt[i] = 0;
    __syncthreads();
    long long e0 = (long long)blockIdx.x * EPW;
    long long e1 = e0 + EPW; if (e1 > NE) e1 = NE;
    for (long long e = e0 + threadIdx.x; e < e1; e += blockDim.x)
        atomicAdd(&cnt[col[e] >> 10], 1);
    __syncthreads();
    for (int i = threadIdx.x; i < NB; i += blockDim.x)
        if (cnt[i]) atomicAdd(&bucketCount[i], cnt[i]);
}

__global__ void k_zero_int(int* __restrict__ p, int n) {
    int i = blockIdx.x * blockDim.x + threadIdx.x;
    if (i < n) p[i] = 0;
}

// ---------- build step 2: scan bucket counts (single block, 1024 thr) ----------

__global__ void k_scan_buckets(const int* __restrict__ bucketCount,
                               int* __restrict__ bucketBase,
                               int* __restrict__ bucketCursor) {
    __shared__ int sm[1024];
    int t = threadIdx.x;
    int v = (t < NB) ? bucketCount[t] : 0;
    sm[t] = v;
    __syncthreads();
    for (int off = 1; off < 1024; off <<= 1) {
        int x = (t >= off) ? sm[t - off] : 0;
        __syncthreads();
        sm[t] += x;
        __syncthreads();
    }
    if (t < NB) {
        int excl = sm[t] - v;
        bucketBase[t] = excl;
        bucketCursor[t] = excl;
    }
    if (t == 0) bucketBase[NB] = NE;
}

// ---------- build step 3: bin edges into bucket-contiguous packed entries ----------
// entry = (row << 10) | (col & 1023); row < 2^20, so 30 bits total.

__global__ void k_bin(const int* __restrict__ row, const int* __restrict__ col,
                      int* __restrict__ bucketCursor, unsigned* __restrict__ binned) {
    __shared__ int cnt[NB];
    __shared__ int base[NB];
    for (int i = threadIdx.x; i < NB; i += blockDim.x) cnt[i] = 0;
    __syncthreads();
    long long e0 = (long long)blockIdx.x * EPW;
    long long e1 = e0 + EPW; if (e1 > NE) e1 = NE;
    for (long long e = e0 + threadIdx.x; e < e1; e += blockDim.x)
        atomicAdd(&cnt[col[e] >> 10], 1);
    __syncthreads();
    for (int i = threadIdx.x; i < NB; i += blockDim.x) {
        int c = cnt[i];
        if (c) base[i] = atomicAdd(&bucketCursor[i], c);
        cnt[i] = 0;  // reuse as running offset
    }
    __syncthreads();
    for (long long e = e0 + threadIdx.x; e < e1; e += blockDim.x) {
        int c = col[e];
        int b = c >> 10;
        int o = atomicAdd(&cnt[b], 1);
        binned[base[b] + o] = ((unsigned)row[e] << 10) | (unsigned)(c & 1023);
    }
}

// ---------- build step 4: per-bucket degree (LDS counters, no global atomics) ----

__global__ void k_bucket_deg(const unsigned* __restrict__ binned,
                             const int* __restrict__ bucketBase,
                             int* __restrict__ deg) {
    __shared__ int cnt[1024];
    int b = blockIdx.x;
    for (int i = threadIdx.x; i < 1024; i += blockDim.x) cnt[i] = 0;
    __syncthreads();
    int i0 = bucketBase[b], i1 = bucketBase[b + 1];
    for (int i = i0 + threadIdx.x; i < i1; i += blockDim.x)
        atomicAdd(&cnt[binned[i] & 1023u], 1);
    __syncthreads();
    int nodeBase = b << 10;
    for (int i = threadIdx.x; i < 1024; i += blockDim.x) {
        int n = nodeBase + i;
        if (n < NN) deg[n] = cnt[i];
    }
}

// ---------- build step 5: exclusive scan of deg -> ptr (3 kernels) ----------

__global__ void k_block_sums(const int* __restrict__ deg, int* __restrict__ bsums) {
    __shared__ int sm[SCAN_THREADS];
    int t = threadIdx.x;
    int base = blockIdx.x * SCAN_BLK + t * 4;
    int s = 0;
#pragma unroll
    for (int k = 0; k < 4; ++k) {
        int idx = base + k;
        if (idx < NN) s += deg[idx];
    }
    sm[t] = s;
    __syncthreads();
    for (int off = SCAN_THREADS / 2; off > 0; off >>= 1) {
        if (t < off) sm[t] += sm[t + off];
        __syncthreads();
    }
    if (t == 0) bsums[blockIdx.x] = sm[0];
}

__global__ void k_scan_bsums(int* __restrict__ bsums, int n) {  // one block, 1024 thr
    __shared__ int sm[1024];
    int t = threadIdx.x;
    sm[t] = (t < n) ? bsums[t] : 0;
    __syncthreads();
    for (int off = 1; off < 1024; off <<= 1) {
        int x = (t >= off) ? sm[t - off] : 0;
        __syncthreads();
        sm[t] += x;
        __syncthreads();
    }
    if (t < n) bsums[t] = (t == 0) ? 0 : sm[t - 1];  // exclusive
}

__global__ void k_scan_final(const int* __restrict__ deg, const int* __restrict__ boff,
                             int* __restrict__ ptr) {
    __shared__ int sm[SCAN_THREADS];
    int t = threadIdx.x;
    int base = blockIdx.x * SCAN_BLK + t * 4;
    int s = 0;
#pragma unroll
    for (int k = 0; k < 4; ++k) {
        int idx = base + k;
        if (idx < NN) s += deg[idx];
    }
    sm[t] = s;
    __syncthreads();
    for (int off = 1; off < SCAN_THREADS; off <<= 1) {
        int x = (t >= off) ? sm[t - off] : 0;
        __syncthreads();
        sm[t] += x;
        __syncthreads();
    }
    int running = boff[blockIdx.x] + ((t == 0) ? 0 : sm[t - 1]);
#pragma unroll
    for (int k = 0; k < 4; ++k) {
        int idx = base + k;
        if (idx < NN) { ptr[idx] = running; running += deg[idx]; }
    }
    if (blockIdx.x == 0 && t == 0) ptr[NN] = NE;
}

// ---------- build step 6: per-bucket scatter (LDS cursors, L2-local writes) ----

__global__ void k_bucket_scatter(const unsigned* __restrict__ binned,
                                 const int* __restrict__ bucketBase,
                                 const int* __restrict__ ptr,
                                 int* __restrict__ sortedRow) {
    __shared__ int cur[1024];
    int b = blockIdx.x;
    int nodeBase = b << 10;
    for (int i = threadIdx.x; i < 1024; i += blockDim.x) {
        int n = nodeBase + i;
        cur[i] = (n < NN) ? ptr[n] : 0;
    }
    __syncthreads();
    int i0 = bucketBase[b], i1 = bucketBase[b + 1];
    for (int i = i0 + threadIdx.x; i < i1; i += blockDim.x) {
        unsigned e = binned[i];
        int pos = atomicAdd(&cur[e & 1023u], 1);
        sortedRow[pos] = (int)(e >> 10);
    }
}

// ---------- dis = rsqrt(deg+1) ----------

__global__ void k_dis(const int* __restrict__ deg, float* __restrict__ dis) {
    int i = blockIdx.x * blockDim.x + threadIdx.x;
    if (i < NN) dis[i] = rsqrtf((float)(deg[i] + 1));  // +1 self-loop
}

// ---------- layer 1 linear: g1 = (x @ W1) * dis  (stride PAD) ----------

__global__ void k_lin1(const float* __restrict__ x, const float* __restrict__ W1,
                       const float* __restrict__ dis, float* __restrict__ g1) {
    __shared__ float w[144];  // 9x16
    if (threadIdx.x < 144) w[threadIdx.x] = W1[threadIdx.x];
    __syncthreads();
    int i = blockIdx.x * blockDim.x + threadIdx.x;
    if (i >= NN) return;
    float xv[9];
#pragma unroll
    for (int k = 0; k < 9; ++k) xv[k] = x[(long long)i * 9 + k];
    float d = dis[i];
#pragma unroll
    for (int j = 0; j < 16; ++j) {
        float acc = 0.f;
#pragma unroll
        for (int k = 0; k < 9; ++k) acc = fmaf(xv[k], w[k * 16 + j], acc);
        g1[(long long)i * PAD + j] = acc * d;
    }
}

// ---------- pull aggregation: agg[n] = dis[n] * (g[n] + sum_{r in in(n)} g[r]) --

template <int F, int AGG_STRIDE>
__global__ void k_pull(const int* __restrict__ ptr, const int* __restrict__ sortedRow,
                       const float* __restrict__ dis, const float* __restrict__ g,
                       float* __restrict__ agg) {
    int grp = threadIdx.x >> 4;
    int j = threadIdx.x & 15;
    int n = blockIdx.x * 16 + grp;
    if (n >= NN) return;
    float acc = 0.f;
    if (j < F) acc = g[(long long)n * PAD + j];  // self-loop term
    int e0 = ptr[n], e1 = ptr[n + 1];
    for (int e = e0; e < e1; ++e) {
        int r = sortedRow[e];  // 16-lane broadcast
        if (j < F) acc += g[(long long)r * PAD + j];
    }
    if (j < F) agg[(long long)n * AGG_STRIDE + j] = dis[n] * acc;
}

// ---------- layer 2 linear (in-place): g2 = relu(agg1+b1) @ W2 * dis ----------

__global__ void k_lin2(float* __restrict__ agg1g2, const float* __restrict__ b1,
                       const float* __restrict__ W2, const float* __restrict__ dis) {
    __shared__ float w[160];  // 16x10
    __shared__ float bb[16];
    if (threadIdx.x < 160) w[threadIdx.x] = W2[threadIdx.x];
    if (threadIdx.x < 16) bb[threadIdx.x] = b1[threadIdx.x];
    __syncthreads();
    int i = blockIdx.x * blockDim.x + threadIdx.x;
    if (i >= NN) return;
    float hv[16];
#pragma unroll
    for (int k = 0; k < 16; ++k)
        hv[k] = fmaxf(agg1g2[(long long)i * PAD + k] + bb[k], 0.f);
    float d = dis[i];
#pragma unroll
    for (int j = 0; j < 10; ++j) {
        float acc = 0.f;
#pragma unroll
        for (int k = 0; k < 16; ++k) acc = fmaf(hv[k], w[k * 10 + j], acc);
        agg1g2[(long long)i * PAD + j] = acc * d;  // in-place: read-all-then-write
    }
}

// ---------- final: out = (agg2 + b2) @ Wf + bf ----------

__global__ void k_final(const float* __restrict__ agg2, const float* __restrict__ b2,
                        const float* __restrict__ Wf, const float* __restrict__ bf,
                        float* __restrict__ out) {
    __shared__ float w[10];
    __shared__ float bb[10];
    __shared__ float bfv;
    if (threadIdx.x < 10) { w[threadIdx.x] = Wf[threadIdx.x]; bb[threadIdx.x] = b2[threadIdx.x]; }
    if (threadIdx.x == 0) bfv = bf[0];
    __syncthreads();
    int i = blockIdx.x * blockDim.x + threadIdx.x;
    if (i >= NN) return;
    float acc = bfv;
#pragma unroll
    for (int j = 0; j < 10; ++j)
        acc = fmaf(agg2[(long long)i * 10 + j] + bb[j], w[j], acc);
    out[i] = acc;
}

extern "C" void kernel_launch(void* const* d_in, const int* in_sizes, int n_in,
                              void* d_out, int out_size, void* d_ws, size_t ws_size,
                              hipStream_t stream) {
    const float* x  = (const float*)d_in[0];
    const int*   ei = (const int*)d_in[1];
    const float* W1 = (const float*)d_in[2];
    const float* b1 = (const float*)d_in[3];
    const float* W2 = (const float*)d_in[4];
    const float* b2 = (const float*)d_in[5];
    const float* Wf = (const float*)d_in[6];
    const float* bf = (const float*)d_in[7];
    float* out = (float*)d_out;

    const int* row = ei;
    const int* col = ei + NE;

    char* ws = (char*)d_ws;
    size_t off = 0;
    auto alloc = [&](size_t bytes) -> void* {
        void* p = ws + off;
        off += (bytes + 255) & ~255ULL;
        return p;
    };
    int* deg          = (int*)alloc((size_t)NN * 4);
    int* ptr          = (int*)alloc((size_t)(NN + 1) * 4);
    float* dis        = (float*)alloc((size_t)NN * 4);
    int* bucketCount  = (int*)alloc((size_t)NB * 4);
    int* bucketBase   = (int*)alloc((size_t)(NB + 1) * 4);
    int* bucketCursor = (int*)alloc((size_t)NB * 4);
    int* bsums        = (int*)alloc((size_t)NSCAN * 4);
    int* sortedRow    = (int*)alloc((size_t)NE * 4);
    unsigned* binned  = (unsigned*)alloc((size_t)NE * 4);  // aliased as g1, then agg2
    float* agg1       = (float*)alloc((size_t)NN * PAD * 4);

    float* g1   = (float*)binned;  // binned dead after k_bucket_scatter
    float* agg2 = g1;              // g1 dead after first k_pull

    const int TB = 256;
    const int nodeGrid = (NN + TB - 1) / TB;
    const int pullGrid = (NN + 15) / 16;

    k_zero_int<<<(NB + TB - 1) / TB, TB, 0, stream>>>(bucketCount, NB);
    k_bincount<<<NWG_BIN, TB, 0, stream>>>(col, bucketCount);
    k_scan_buckets<<<1, 1024, 0, stream>>>(bucketCount, bucketBase, bucketCursor);
    k_bin<<<NWG_BIN, TB, 0, stream>>>(row, col, bucketCursor, binned);
    k_bucket_deg<<<NB, TB, 0, stream>>>(binned, bucketBase, deg);
    k_block_sums<<<NSCAN, SCAN_THREADS, 0, stream>>>(deg, bsums);
    k_scan_bsums<<<1, 1024, 0, stream>>>(bsums, NSCAN);
    k_scan_final<<<NSCAN, SCAN_THREADS, 0, stream>>>(deg, bsums, ptr);
    k_bucket_scatter<<<NB, TB, 0, stream>>>(binned, bucketBase, ptr, sortedRow);
    k_dis<<<nodeGrid, TB, 0, stream>>>(deg, dis);

    k_lin1<<<nodeGrid, TB, 0, stream>>>(x, W1, dis, g1);
    k_pull<16, PAD><<<pullGrid, TB, 0, stream>>>(ptr, sortedRow, dis, g1, agg1);
    k_lin2<<<nodeGrid, TB, 0, stream>>>(agg1, b1, W2, dis);  // agg1 -> g2 in place
    k_pull<10, 10><<<pullGrid, TB, 0, stream>>>(ptr, sortedRow, dis, agg1, agg2);
    k_final<<<nodeGrid, TB, 0, stream>>>(agg2, b2, Wf, bf, out);
}

// Round 5
// 1275.790 us; speedup vs baseline: 2.2710x; 1.2761x over previous
//
#include <hip/hip_runtime.h>

static constexpr int NN = 1000000;
static constexpr int NE = 16000000;
static constexpr int PAD = 16;                 // feature stride for gather arrays
static constexpr int NB = (NN + 1023) >> 10;   // 977 buckets of 1024 nodes
static constexpr int NWG_BIN = 512;
static constexpr int EPW = NE / NWG_BIN;       // 31250 edges per binning workgroup

static constexpr int SCAN_BLK = 1024;
static constexpr int SCAN_THREADS = 256;
static constexpr int NSCAN = (NN + SCAN_BLK - 1) / SCAN_BLK;  // 977

// ---------- build step 1: per-bucket edge counts (LDS histogram) ----------

__global__ void k_bincount(const int* __restrict__ col, int* __restrict__ bucketCount) {
    __shared__ int cnt[NB];
    for (int i = threadIdx.x; i < NB; i += blockDim.x) cnt[i] = 0;
    __syncthreads();
    long long e0 = (long long)blockIdx.x * EPW;
    long long e1 = e0 + EPW; if (e1 > NE) e1 = NE;
    for (long long e = e0 + threadIdx.x; e < e1; e += blockDim.x)
        atomicAdd(&cnt[col[e] >> 10], 1);
    __syncthreads();
    for (int i = threadIdx.x; i < NB; i += blockDim.x)
        if (cnt[i]) atomicAdd(&bucketCount[i], cnt[i]);
}

__global__ void k_zero_int(int* __restrict__ p, int n) {
    int i = blockIdx.x * blockDim.x + threadIdx.x;
    if (i < n) p[i] = 0;
}

// ---------- build step 2: scan bucket counts (single block, 1024 thr) ----------

__global__ void k_scan_buckets(const int* __restrict__ bucketCount,
                               int* __restrict__ bucketBase,
                               int* __restrict__ bucketCursor) {
    __shared__ int sm[1024];
    int t = threadIdx.x;
    int v = (t < NB) ? bucketCount[t] : 0;
    sm[t] = v;
    __syncthreads();
    for (int off = 1; off < 1024; off <<= 1) {
        int x = (t >= off) ? sm[t - off] : 0;
        __syncthreads();
        sm[t] += x;
        __syncthreads();
    }
    if (t < NB) {
        int excl = sm[t] - v;
        bucketBase[t] = excl;
        bucketCursor[t] = excl;
    }
    if (t == 0) bucketBase[NB] = NE;
}

// ---------- build step 3: bin edges into bucket-contiguous packed entries ----------
// entry = (row << 10) | (col & 1023); row < 2^20, so 30 bits total.

__global__ void k_bin(const int* __restrict__ row, const int* __restrict__ col,
                      int* __restrict__ bucketCursor, unsigned* __restrict__ binned) {
    __shared__ int cnt[NB];
    __shared__ int base[NB];
    for (int i = threadIdx.x; i < NB; i += blockDim.x) cnt[i] = 0;
    __syncthreads();
    long long e0 = (long long)blockIdx.x * EPW;
    long long e1 = e0 + EPW; if (e1 > NE) e1 = NE;
    for (long long e = e0 + threadIdx.x; e < e1; e += blockDim.x)
        atomicAdd(&cnt[col[e] >> 10], 1);
    __syncthreads();
    for (int i = threadIdx.x; i < NB; i += blockDim.x) {
        int c = cnt[i];
        if (c) base[i] = atomicAdd(&bucketCursor[i], c);
        cnt[i] = 0;  // reuse as running offset
    }
    __syncthreads();
    for (long long e = e0 + threadIdx.x; e < e1; e += blockDim.x) {
        int c = col[e];
        int b = c >> 10;
        int o = atomicAdd(&cnt[b], 1);
        binned[base[b] + o] = ((unsigned)row[e] << 10) | (unsigned)(c & 1023);
    }
}

// ---------- build step 4: per-bucket degree (LDS counters, no global atomics) ----

__global__ void k_bucket_deg(const unsigned* __restrict__ binned,
                             const int* __restrict__ bucketBase,
                             int* __restrict__ deg) {
    __shared__ int cnt[1024];
    int b = blockIdx.x;
    for (int i = threadIdx.x; i < 1024; i += blockDim.x) cnt[i] = 0;
    __syncthreads();
    int i0 = bucketBase[b], i1 = bucketBase[b + 1];
    for (int i = i0 + threadIdx.x; i < i1; i += blockDim.x)
        atomicAdd(&cnt[binned[i] & 1023u], 1);
    __syncthreads();
    int nodeBase = b << 10;
    for (int i = threadIdx.x; i < 1024; i += blockDim.x) {
        int n = nodeBase + i;
        if (n < NN) deg[n] = cnt[i];
    }
}

// ---------- build step 5: exclusive scan of deg -> ptr (3 kernels) ----------

__global__ void k_block_sums(const int* __restrict__ deg, int* __restrict__ bsums) {
    __shared__ int sm[SCAN_THREADS];
    int t = threadIdx.x;
    int base = blockIdx.x * SCAN_BLK + t * 4;
    int s = 0;
#pragma unroll
    for (int k = 0; k < 4; ++k) {
        int idx = base + k;
        if (idx < NN) s += deg[idx];
    }
    sm[t] = s;
    __syncthreads();
    for (int off = SCAN_THREADS / 2; off > 0; off >>= 1) {
        if (t < off) sm[t] += sm[t + off];
        __syncthreads();
    }
    if (t == 0) bsums[blockIdx.x] = sm[0];
}

__global__ void k_scan_bsums(int* __restrict__ bsums, int n) {  // one block, 1024 thr
    __shared__ int sm[1024];
    int t = threadIdx.x;
    sm[t] = (t < n) ? bsums[t] : 0;
    __syncthreads();
    for (int off = 1; off < 1024; off <<= 1) {
        int x = (t >= off) ? sm[t - off] : 0;
        __syncthreads();
        sm[t] += x;
        __syncthreads();
    }
    if (t < n) bsums[t] = (t == 0) ? 0 : sm[t - 1];  // exclusive
}

__global__ void k_scan_final(const int* __restrict__ deg, const int* __restrict__ boff,
                             int* __restrict__ ptr) {
    __shared__ int sm[SCAN_THREADS];
    int t = threadIdx.x;
    int base = blockIdx.x * SCAN_BLK + t * 4;
    int s = 0;
#pragma unroll
    for (int k = 0; k < 4; ++k) {
        int idx = base + k;
        if (idx < NN) s += deg[idx];
    }
    sm[t] = s;
    __syncthreads();
    for (int off = 1; off < SCAN_THREADS; off <<= 1) {
        int x = (t >= off) ? sm[t - off] : 0;
        __syncthreads();
        sm[t] += x;
        __syncthreads();
    }
    int running = boff[blockIdx.x] + ((t == 0) ? 0 : sm[t - 1]);
#pragma unroll
    for (int k = 0; k < 4; ++k) {
        int idx = base + k;
        if (idx < NN) { ptr[idx] = running; running += deg[idx]; }
    }
    if (blockIdx.x == 0 && t == 0) ptr[NN] = NE;
}

// ---------- build step 6: per-bucket scatter (LDS cursors, L2-local writes) ----

__global__ void k_bucket_scatter(const unsigned* __restrict__ binned,
                                 const int* __restrict__ bucketBase,
                                 const int* __restrict__ ptr,
                                 int* __restrict__ sortedRow) {
    __shared__ int cur[1024];
    int b = blockIdx.x;
    int nodeBase = b << 10;
    for (int i = threadIdx.x; i < 1024; i += blockDim.x) {
        int n = nodeBase + i;
        cur[i] = (n < NN) ? ptr[n] : 0;
    }
    __syncthreads();
    int i0 = bucketBase[b], i1 = bucketBase[b + 1];
    for (int i = i0 + threadIdx.x; i < i1; i += blockDim.x) {
        unsigned e = binned[i];
        int pos = atomicAdd(&cur[e & 1023u], 1);
        sortedRow[pos] = (int)(e >> 10);
    }
}

// ---------- dis = rsqrt(deg+1) ----------

__global__ void k_dis(const int* __restrict__ deg, float* __restrict__ dis) {
    int i = blockIdx.x * blockDim.x + threadIdx.x;
    if (i < NN) dis[i] = rsqrtf((float)(deg[i] + 1));  // +1 self-loop
}

// ---------- layer 1 linear: g1 = (x @ W1) * dis  (stride PAD) ----------

__global__ void k_lin1(const float* __restrict__ x, const float* __restrict__ W1,
                       const float* __restrict__ dis, float* __restrict__ g1) {
    __shared__ float w[144];  // 9x16
    if (threadIdx.x < 144) w[threadIdx.x] = W1[threadIdx.x];
    __syncthreads();
    int i = blockIdx.x * blockDim.x + threadIdx.x;
    if (i >= NN) return;
    float xv[9];
#pragma unroll
    for (int k = 0; k < 9; ++k) xv[k] = x[(long long)i * 9 + k];
    float d = dis[i];
#pragma unroll
    for (int j = 0; j < 16; ++j) {
        float acc = 0.f;
#pragma unroll
        for (int k = 0; k < 9; ++k) acc = fmaf(xv[k], w[k * 16 + j], acc);
        g1[(long long)i * PAD + j] = acc * d;
    }
}

// ---------- pull aggregation: agg[n] = dis[n] * (g[n] + sum_{r in in(n)} g[r]) --
// 16 lanes/node. 8-deep unrolled gather loop for memory-level parallelism.
// Lanes j >= F read in-bounds stale floats (finite) and never write — no guard.

template <int F, int AGG_STRIDE>
__global__ void k_pull(const int* __restrict__ ptr, const int* __restrict__ sortedRow,
                       const float* __restrict__ dis, const float* __restrict__ g,
                       float* __restrict__ agg) {
    int grp = threadIdx.x >> 4;
    int j = threadIdx.x & 15;
    int n = blockIdx.x * 16 + grp;
    if (n >= NN) return;
    int e0 = ptr[n], e1 = ptr[n + 1];
    float acc = g[(long long)n * PAD + j];  // self-loop term
    int e = e0;
    for (; e + 8 <= e1; e += 8) {
        int r0 = sortedRow[e + 0], r1 = sortedRow[e + 1];
        int r2 = sortedRow[e + 2], r3 = sortedRow[e + 3];
        int r4 = sortedRow[e + 4], r5 = sortedRow[e + 5];
        int r6 = sortedRow[e + 6], r7 = sortedRow[e + 7];
        float v0 = g[(long long)r0 * PAD + j];
        float v1 = g[(long long)r1 * PAD + j];
        float v2 = g[(long long)r2 * PAD + j];
        float v3 = g[(long long)r3 * PAD + j];
        float v4 = g[(long long)r4 * PAD + j];
        float v5 = g[(long long)r5 * PAD + j];
        float v6 = g[(long long)r6 * PAD + j];
        float v7 = g[(long long)r7 * PAD + j];
        acc += ((v0 + v1) + (v2 + v3)) + ((v4 + v5) + (v6 + v7));
    }
    for (; e + 4 <= e1; e += 4) {
        int r0 = sortedRow[e + 0], r1 = sortedRow[e + 1];
        int r2 = sortedRow[e + 2], r3 = sortedRow[e + 3];
        float v0 = g[(long long)r0 * PAD + j];
        float v1 = g[(long long)r1 * PAD + j];
        float v2 = g[(long long)r2 * PAD + j];
        float v3 = g[(long long)r3 * PAD + j];
        acc += (v0 + v1) + (v2 + v3);
    }
    for (; e < e1; ++e)
        acc += g[(long long)sortedRow[e] * PAD + j];
    if (j < F) agg[(long long)n * AGG_STRIDE + j] = dis[n] * acc;
}

// ---------- layer 2 linear (in-place): g2 = relu(agg1+b1) @ W2 * dis ----------

__global__ void k_lin2(float* __restrict__ agg1g2, const float* __restrict__ b1,
                       const float* __restrict__ W2, const float* __restrict__ dis) {
    __shared__ float w[160];  // 16x10
    __shared__ float bb[16];
    if (threadIdx.x < 160) w[threadIdx.x] = W2[threadIdx.x];
    if (threadIdx.x < 16) bb[threadIdx.x] = b1[threadIdx.x];
    __syncthreads();
    int i = blockIdx.x * blockDim.x + threadIdx.x;
    if (i >= NN) return;
    float hv[16];
#pragma unroll
    for (int k = 0; k < 16; ++k)
        hv[k] = fmaxf(agg1g2[(long long)i * PAD + k] + bb[k], 0.f);
    float d = dis[i];
#pragma unroll
    for (int j = 0; j < 10; ++j) {
        float acc = 0.f;
#pragma unroll
        for (int k = 0; k < 16; ++k) acc = fmaf(hv[k], w[k * 10 + j], acc);
        agg1g2[(long long)i * PAD + j] = acc * d;  // in-place: read-all-then-write
    }
}

// ---------- final: out = (agg2 + b2) @ Wf + bf ----------

__global__ void k_final(const float* __restrict__ agg2, const float* __restrict__ b2,
                        const float* __restrict__ Wf, const float* __restrict__ bf,
                        float* __restrict__ out) {
    __shared__ float w[10];
    __shared__ float bb[10];
    __shared__ float bfv;
    if (threadIdx.x < 10) { w[threadIdx.x] = Wf[threadIdx.x]; bb[threadIdx.x] = b2[threadIdx.x]; }
    if (threadIdx.x == 0) bfv = bf[0];
    __syncthreads();
    int i = blockIdx.x * blockDim.x + threadIdx.x;
    if (i >= NN) return;
    float acc = bfv;
#pragma unroll
    for (int j = 0; j < 10; ++j)
        acc = fmaf(agg2[(long long)i * 10 + j] + bb[j], w[j], acc);
    out[i] = acc;
}

extern "C" void kernel_launch(void* const* d_in, const int* in_sizes, int n_in,
                              void* d_out, int out_size, void* d_ws, size_t ws_size,
                              hipStream_t stream) {
    const float* x  = (const float*)d_in[0];
    const int*   ei = (const int*)d_in[1];
    const float* W1 = (const float*)d_in[2];
    const float* b1 = (const float*)d_in[3];
    const float* W2 = (const float*)d_in[4];
    const float* b2 = (const float*)d_in[5];
    const float* Wf = (const float*)d_in[6];
    const float* bf = (const float*)d_in[7];
    float* out = (float*)d_out;

    const int* row = ei;
    const int* col = ei + NE;

    char* ws = (char*)d_ws;
    size_t off = 0;
    auto alloc = [&](size_t bytes) -> void* {
        void* p = ws + off;
        off += (bytes + 255) & ~255ULL;
        return p;
    };
    int* deg          = (int*)alloc((size_t)NN * 4);
    int* ptr          = (int*)alloc((size_t)(NN + 1) * 4);
    float* dis        = (float*)alloc((size_t)NN * 4);
    int* bucketCount  = (int*)alloc((size_t)NB * 4);
    int* bucketBase   = (int*)alloc((size_t)(NB + 1) * 4);
    int* bucketCursor = (int*)alloc((size_t)NB * 4);
    int* bsums        = (int*)alloc((size_t)NSCAN * 4);
    int* sortedRow    = (int*)alloc((size_t)NE * 4);
    unsigned* binned  = (unsigned*)alloc((size_t)NE * 4);  // aliased as g1, then agg2
    float* agg1       = (float*)alloc((size_t)NN * PAD * 4);

    float* g1   = (float*)binned;  // binned dead after k_bucket_scatter
    float* agg2 = g1;              // g1 dead after first k_pull

    const int TB = 256;
    const int nodeGrid = (NN + TB - 1) / TB;
    const int pullGrid = (NN + 15) / 16;

    k_zero_int<<<(NB + TB - 1) / TB, TB, 0, stream>>>(bucketCount, NB);
    k_bincount<<<NWG_BIN, TB, 0, stream>>>(col, bucketCount);
    k_scan_buckets<<<1, 1024, 0, stream>>>(bucketCount, bucketBase, bucketCursor);
    k_bin<<<NWG_BIN, TB, 0, stream>>>(row, col, bucketCursor, binned);
    k_bucket_deg<<<NB, TB, 0, stream>>>(binned, bucketBase, deg);
    k_block_sums<<<NSCAN, SCAN_THREADS, 0, stream>>>(deg, bsums);
    k_scan_bsums<<<1, 1024, 0, stream>>>(bsums, NSCAN);
    k_scan_final<<<NSCAN, SCAN_THREADS, 0, stream>>>(deg, bsums, ptr);
    k_bucket_scatter<<<NB, TB, 0, stream>>>(binned, bucketBase, ptr, sortedRow);
    k_dis<<<nodeGrid, TB, 0, stream>>>(deg, dis);

    k_lin1<<<nodeGrid, TB, 0, stream>>>(x, W1, dis, g1);
    k_pull<16, PAD><<<pullGrid, TB, 0, stream>>>(ptr, sortedRow, dis, g1, agg1);
    k_lin2<<<nodeGrid, TB, 0, stream>>>(agg1, b1, W2, dis);  // agg1 -> g2 in place
    k_pull<10, 10><<<pullGrid, TB, 0, stream>>>(ptr, sortedRow, dis, agg1, agg2);
    k_final<<<nodeGrid, TB, 0, stream>>>(agg2, b2, Wf, bf, out);
}

// Round 6
// 1117.475 us; speedup vs baseline: 2.5927x; 1.1417x over previous
//
#include <hip/hip_runtime.h>

static constexpr int NN = 1000000;
static constexpr int NE = 16000000;
static constexpr int PAD = 16;                 // feature stride for gather arrays
static constexpr int BSH = 11;                 // bucket shift: 2048-node buckets
static constexpr int BNODES = 1 << BSH;
static constexpr int BMASK = BNODES - 1;
static constexpr int NB = (NN + BMASK) >> BSH; // 489 buckets
static constexpr int NWG_BIN = 512;
static constexpr int EPW = NE / NWG_BIN;       // 31250 edges per binning workgroup

static constexpr int SCAN_BLK = 1024;
static constexpr int SCAN_THREADS = 256;
static constexpr int NSCAN = (NN + SCAN_BLK - 1) / SCAN_BLK;  // 977

// ---------- build step 1: per-bucket edge counts (LDS histogram, x4 unroll) ----

__global__ void k_bincount(const int* __restrict__ col, int* __restrict__ bucketCount) {
    __shared__ int cnt[NB];
    for (int i = threadIdx.x; i < NB; i += blockDim.x) cnt[i] = 0;
    __syncthreads();
    long long e0 = (long long)blockIdx.x * EPW;
    long long e1 = e0 + EPW; if (e1 > NE) e1 = NE;
    long long e = e0 + threadIdx.x;
    for (; e + 768 < e1; e += 1024) {
        int c0 = col[e], c1 = col[e + 256], c2 = col[e + 512], c3 = col[e + 768];
        atomicAdd(&cnt[c0 >> BSH], 1);
        atomicAdd(&cnt[c1 >> BSH], 1);
        atomicAdd(&cnt[c2 >> BSH], 1);
        atomicAdd(&cnt[c3 >> BSH], 1);
    }
    for (; e < e1; e += 256) atomicAdd(&cnt[col[e] >> BSH], 1);
    __syncthreads();
    for (int i = threadIdx.x; i < NB; i += blockDim.x)
        if (cnt[i]) atomicAdd(&bucketCount[i], cnt[i]);
}

__global__ void k_zero_int(int* __restrict__ p, int n) {
    int i = blockIdx.x * blockDim.x + threadIdx.x;
    if (i < n) p[i] = 0;
}

// ---------- build step 2: scan bucket counts (single block, 1024 thr) ----------

__global__ void k_scan_buckets(const int* __restrict__ bucketCount,
                               int* __restrict__ bucketBase,
                               int* __restrict__ bucketCursor) {
    __shared__ int sm[1024];
    int t = threadIdx.x;
    int v = (t < NB) ? bucketCount[t] : 0;
    sm[t] = v;
    __syncthreads();
    for (int off = 1; off < 1024; off <<= 1) {
        int x = (t >= off) ? sm[t - off] : 0;
        __syncthreads();
        sm[t] += x;
        __syncthreads();
    }
    if (t < NB) {
        int excl = sm[t] - v;
        bucketBase[t] = excl;
        bucketCursor[t] = excl;
    }
    if (t == 0) bucketBase[NB] = NE;
}

// ---------- build step 3: bin edges into bucket-contiguous packed entries -------
// entry = (row << 11) | (col & 2047); row < 2^20 -> 31 bits.

__global__ void k_bin(const int* __restrict__ row, const int* __restrict__ col,
                      int* __restrict__ bucketCursor, unsigned* __restrict__ binned) {
    __shared__ int cnt[NB];
    __shared__ int base[NB];
    for (int i = threadIdx.x; i < NB; i += blockDim.x) cnt[i] = 0;
    __syncthreads();
    long long e0 = (long long)blockIdx.x * EPW;
    long long e1 = e0 + EPW; if (e1 > NE) e1 = NE;
    long long e = e0 + threadIdx.x;
    for (; e + 768 < e1; e += 1024) {
        int c0 = col[e], c1 = col[e + 256], c2 = col[e + 512], c3 = col[e + 768];
        atomicAdd(&cnt[c0 >> BSH], 1);
        atomicAdd(&cnt[c1 >> BSH], 1);
        atomicAdd(&cnt[c2 >> BSH], 1);
        atomicAdd(&cnt[c3 >> BSH], 1);
    }
    for (; e < e1; e += 256) atomicAdd(&cnt[col[e] >> BSH], 1);
    __syncthreads();
    for (int i = threadIdx.x; i < NB; i += blockDim.x) {
        int c = cnt[i];
        if (c) base[i] = atomicAdd(&bucketCursor[i], c);
        cnt[i] = 0;  // reuse as running offset
    }
    __syncthreads();
    e = e0 + threadIdx.x;
    for (; e + 768 < e1; e += 1024) {
        int c0 = col[e],       r0 = row[e];
        int c1 = col[e + 256], r1 = row[e + 256];
        int c2 = col[e + 512], r2 = row[e + 512];
        int c3 = col[e + 768], r3 = row[e + 768];
        int b0 = c0 >> BSH, b1 = c1 >> BSH, b2 = c2 >> BSH, b3 = c3 >> BSH;
        int o0 = atomicAdd(&cnt[b0], 1);
        int o1 = atomicAdd(&cnt[b1], 1);
        int o2 = atomicAdd(&cnt[b2], 1);
        int o3 = atomicAdd(&cnt[b3], 1);
        binned[base[b0] + o0] = ((unsigned)r0 << BSH) | (unsigned)(c0 & BMASK);
        binned[base[b1] + o1] = ((unsigned)r1 << BSH) | (unsigned)(c1 & BMASK);
        binned[base[b2] + o2] = ((unsigned)r2 << BSH) | (unsigned)(c2 & BMASK);
        binned[base[b3] + o3] = ((unsigned)r3 << BSH) | (unsigned)(c3 & BMASK);
    }
    for (; e < e1; e += 256) {
        int c = col[e];
        int b = c >> BSH;
        int o = atomicAdd(&cnt[b], 1);
        binned[base[b] + o] = ((unsigned)row[e] << BSH) | (unsigned)(c & BMASK);
    }
}

// ---------- build step 4: per-bucket degree (LDS counters) ----------

__global__ void k_bucket_deg(const unsigned* __restrict__ binned,
                             const int* __restrict__ bucketBase,
                             int* __restrict__ deg) {
    __shared__ int cnt[BNODES];
    int b = blockIdx.x;
    for (int i = threadIdx.x; i < BNODES; i += blockDim.x) cnt[i] = 0;
    __syncthreads();
    int i0 = bucketBase[b], i1 = bucketBase[b + 1];
    int i = i0 + threadIdx.x;
    for (; i + 768 < i1; i += 1024) {
        unsigned v0 = binned[i], v1 = binned[i + 256];
        unsigned v2 = binned[i + 512], v3 = binned[i + 768];
        atomicAdd(&cnt[v0 & BMASK], 1);
        atomicAdd(&cnt[v1 & BMASK], 1);
        atomicAdd(&cnt[v2 & BMASK], 1);
        atomicAdd(&cnt[v3 & BMASK], 1);
    }
    for (; i < i1; i += 256) atomicAdd(&cnt[binned[i] & BMASK], 1);
    __syncthreads();
    int nodeBase = b << BSH;
    for (int k = threadIdx.x; k < BNODES; k += blockDim.x) {
        int n = nodeBase + k;
        if (n < NN) deg[n] = cnt[k];
    }
}

// ---------- build step 5: exclusive scan of deg -> ptr (3 kernels) ----------

__global__ void k_block_sums(const int* __restrict__ deg, int* __restrict__ bsums) {
    __shared__ int sm[SCAN_THREADS];
    int t = threadIdx.x;
    int base = blockIdx.x * SCAN_BLK + t * 4;
    int s = 0;
#pragma unroll
    for (int k = 0; k < 4; ++k) {
        int idx = base + k;
        if (idx < NN) s += deg[idx];
    }
    sm[t] = s;
    __syncthreads();
    for (int off = SCAN_THREADS / 2; off > 0; off >>= 1) {
        if (t < off) sm[t] += sm[t + off];
        __syncthreads();
    }
    if (t == 0) bsums[blockIdx.x] = sm[0];
}

__global__ void k_scan_bsums(int* __restrict__ bsums, int n) {  // one block, 1024 thr
    __shared__ int sm[1024];
    int t = threadIdx.x;
    sm[t] = (t < n) ? bsums[t] : 0;
    __syncthreads();
    for (int off = 1; off < 1024; off <<= 1) {
        int x = (t >= off) ? sm[t - off] : 0;
        __syncthreads();
        sm[t] += x;
        __syncthreads();
    }
    if (t < n) bsums[t] = (t == 0) ? 0 : sm[t - 1];  // exclusive
}

__global__ void k_scan_final(const int* __restrict__ deg, const int* __restrict__ boff,
                             int* __restrict__ ptr) {
    __shared__ int sm[SCAN_THREADS];
    int t = threadIdx.x;
    int base = blockIdx.x * SCAN_BLK + t * 4;
    int s = 0;
#pragma unroll
    for (int k = 0; k < 4; ++k) {
        int idx = base + k;
        if (idx < NN) s += deg[idx];
    }
    sm[t] = s;
    __syncthreads();
    for (int off = 1; off < SCAN_THREADS; off <<= 1) {
        int x = (t >= off) ? sm[t - off] : 0;
        __syncthreads();
        sm[t] += x;
        __syncthreads();
    }
    int running = boff[blockIdx.x] + ((t == 0) ? 0 : sm[t - 1]);
#pragma unroll
    for (int k = 0; k < 4; ++k) {
        int idx = base + k;
        if (idx < NN) { ptr[idx] = running; running += deg[idx]; }
    }
    if (blockIdx.x == 0 && t == 0) ptr[NN] = NE;
}

// ---------- build step 6: per-bucket scatter (LDS cursors, L2-local writes) ----

__global__ void k_bucket_scatter(const unsigned* __restrict__ binned,
                                 const int* __restrict__ bucketBase,
                                 const int* __restrict__ ptr,
                                 int* __restrict__ sortedRow) {
    __shared__ int cur[BNODES];
    int b = blockIdx.x;
    int nodeBase = b << BSH;
    for (int i = threadIdx.x; i < BNODES; i += blockDim.x) {
        int n = nodeBase + i;
        cur[i] = (n < NN) ? ptr[n] : 0;
    }
    __syncthreads();
    int i0 = bucketBase[b], i1 = bucketBase[b + 1];
    int i = i0 + threadIdx.x;
    for (; i + 768 < i1; i += 1024) {
        unsigned v0 = binned[i],       v1 = binned[i + 256];
        unsigned v2 = binned[i + 512], v3 = binned[i + 768];
        int p0 = atomicAdd(&cur[v0 & BMASK], 1);
        int p1 = atomicAdd(&cur[v1 & BMASK], 1);
        int p2 = atomicAdd(&cur[v2 & BMASK], 1);
        int p3 = atomicAdd(&cur[v3 & BMASK], 1);
        sortedRow[p0] = (int)(v0 >> BSH);
        sortedRow[p1] = (int)(v1 >> BSH);
        sortedRow[p2] = (int)(v2 >> BSH);
        sortedRow[p3] = (int)(v3 >> BSH);
    }
    for (; i < i1; i += 256) {
        unsigned v = binned[i];
        int pos = atomicAdd(&cur[v & BMASK], 1);
        sortedRow[pos] = (int)(v >> BSH);
    }
}

// ---------- dis = rsqrt(deg+1) ----------

__global__ void k_dis(const int* __restrict__ deg, float* __restrict__ dis) {
    int i = blockIdx.x * blockDim.x + threadIdx.x;
    if (i < NN) dis[i] = rsqrtf((float)(deg[i] + 1));  // +1 self-loop
}

// ---------- layer 1 linear: g1 = (x @ W1) * dis  (stride PAD) ----------

__global__ void k_lin1(const float* __restrict__ x, const float* __restrict__ W1,
                       const float* __restrict__ dis, float* __restrict__ g1) {
    __shared__ float w[144];  // 9x16
    if (threadIdx.x < 144) w[threadIdx.x] = W1[threadIdx.x];
    __syncthreads();
    int i = blockIdx.x * blockDim.x + threadIdx.x;
    if (i >= NN) return;
    float xv[9];
#pragma unroll
    for (int k = 0; k < 9; ++k) xv[k] = x[(long long)i * 9 + k];
    float d = dis[i];
#pragma unroll
    for (int j = 0; j < 16; ++j) {
        float acc = 0.f;
#pragma unroll
        for (int k = 0; k < 9; ++k) acc = fmaf(xv[k], w[k * 16 + j], acc);
        g1[(long long)i * PAD + j] = acc * d;
    }
}

// ---------- pull aggregation: agg[n] = dis[n] * (g[n] + sum_{r in in(n)} g[r]) --
// 16 lanes/node. 16-deep unrolled gather loop for max memory-level parallelism.
// Lanes j >= F read in-bounds stale floats (finite) and never write — no guard.

template <int F, int AGG_STRIDE>
__global__ void k_pull(const int* __restrict__ ptr, const int* __restrict__ sortedRow,
                       const float* __restrict__ dis, const float* __restrict__ g,
                       float* __restrict__ agg) {
    int grp = threadIdx.x >> 4;
    int j = threadIdx.x & 15;
    int n = blockIdx.x * 16 + grp;
    if (n >= NN) return;
    int e0 = ptr[n], e1 = ptr[n + 1];
    float acc = g[(long long)n * PAD + j];  // self-loop term
    int e = e0;
    for (; e + 16 <= e1; e += 16) {
        int r[16];
#pragma unroll
        for (int k = 0; k < 16; ++k) r[k] = sortedRow[e + k];
        float v[16];
#pragma unroll
        for (int k = 0; k < 16; ++k) v[k] = g[(long long)r[k] * PAD + j];
        float s0 = ((v[0] + v[1]) + (v[2] + v[3])) + ((v[4] + v[5]) + (v[6] + v[7]));
        float s1 = ((v[8] + v[9]) + (v[10] + v[11])) + ((v[12] + v[13]) + (v[14] + v[15]));
        acc += s0 + s1;
    }
    for (; e + 4 <= e1; e += 4) {
        int r0 = sortedRow[e + 0], r1 = sortedRow[e + 1];
        int r2 = sortedRow[e + 2], r3 = sortedRow[e + 3];
        float v0 = g[(long long)r0 * PAD + j];
        float v1 = g[(long long)r1 * PAD + j];
        float v2 = g[(long long)r2 * PAD + j];
        float v3 = g[(long long)r3 * PAD + j];
        acc += (v0 + v1) + (v2 + v3);
    }
    for (; e < e1; ++e)
        acc += g[(long long)sortedRow[e] * PAD + j];
    if (j < F) agg[(long long)n * AGG_STRIDE + j] = dis[n] * acc;
}

// ---------- layer 2 linear (in-place): g2 = relu(agg1+b1) @ W2 * dis ----------

__global__ void k_lin2(float* __restrict__ agg1g2, const float* __restrict__ b1,
                       const float* __restrict__ W2, const float* __restrict__ dis) {
    __shared__ float w[160];  // 16x10
    __shared__ float bb[16];
    if (threadIdx.x < 160) w[threadIdx.x] = W2[threadIdx.x];
    if (threadIdx.x < 16) bb[threadIdx.x] = b1[threadIdx.x];
    __syncthreads();
    int i = blockIdx.x * blockDim.x + threadIdx.x;
    if (i >= NN) return;
    float hv[16];
#pragma unroll
    for (int k = 0; k < 16; ++k)
        hv[k] = fmaxf(agg1g2[(long long)i * PAD + k] + bb[k], 0.f);
    float d = dis[i];
#pragma unroll
    for (int j = 0; j < 10; ++j) {
        float acc = 0.f;
#pragma unroll
        for (int k = 0; k < 16; ++k) acc = fmaf(hv[k], w[k * 10 + j], acc);
        agg1g2[(long long)i * PAD + j] = acc * d;  // in-place: read-all-then-write
    }
}

// ---------- final: out = (agg2 + b2) @ Wf + bf ----------

__global__ void k_final(const float* __restrict__ agg2, const float* __restrict__ b2,
                        const float* __restrict__ Wf, const float* __restrict__ bf,
                        float* __restrict__ out) {
    __shared__ float w[10];
    __shared__ float bb[10];
    __shared__ float bfv;
    if (threadIdx.x < 10) { w[threadIdx.x] = Wf[threadIdx.x]; bb[threadIdx.x] = b2[threadIdx.x]; }
    if (threadIdx.x == 0) bfv = bf[0];
    __syncthreads();
    int i = blockIdx.x * blockDim.x + threadIdx.x;
    if (i >= NN) return;
    float acc = bfv;
#pragma unroll
    for (int j = 0; j < 10; ++j)
        acc = fmaf(agg2[(long long)i * 10 + j] + bb[j], w[j], acc);
    out[i] = acc;
}

extern "C" void kernel_launch(void* const* d_in, const int* in_sizes, int n_in,
                              void* d_out, int out_size, void* d_ws, size_t ws_size,
                              hipStream_t stream) {
    const float* x  = (const float*)d_in[0];
    const int*   ei = (const int*)d_in[1];
    const float* W1 = (const float*)d_in[2];
    const float* b1 = (const float*)d_in[3];
    const float* W2 = (const float*)d_in[4];
    const float* b2 = (const float*)d_in[5];
    const float* Wf = (const float*)d_in[6];
    const float* bf = (const float*)d_in[7];
    float* out = (float*)d_out;

    const int* row = ei;
    const int* col = ei + NE;

    char* ws = (char*)d_ws;
    size_t off = 0;
    auto alloc = [&](size_t bytes) -> void* {
        void* p = ws + off;
        off += (bytes + 255) & ~255ULL;
        return p;
    };
    int* deg          = (int*)alloc((size_t)NN * 4);
    int* ptr          = (int*)alloc((size_t)(NN + 1) * 4);
    float* dis        = (float*)alloc((size_t)NN * 4);
    int* bucketCount  = (int*)alloc((size_t)NB * 4);
    int* bucketBase   = (int*)alloc((size_t)(NB + 1) * 4);
    int* bucketCursor = (int*)alloc((size_t)NB * 4);
    int* bsums        = (int*)alloc((size_t)NSCAN * 4);
    int* sortedRow    = (int*)alloc((size_t)NE * 4);
    unsigned* binned  = (unsigned*)alloc((size_t)NE * 4);  // aliased as g1, then agg2
    float* agg1       = (float*)alloc((size_t)NN * PAD * 4);

    float* g1   = (float*)binned;  // binned dead after k_bucket_scatter
    float* agg2 = g1;              // g1 dead after first k_pull

    const int TB = 256;
    const int nodeGrid = (NN + TB - 1) / TB;
    const int pullGrid = (NN + 15) / 16;

    k_zero_int<<<(NB + TB - 1) / TB, TB, 0, stream>>>(bucketCount, NB);
    k_bincount<<<NWG_BIN, TB, 0, stream>>>(col, bucketCount);
    k_scan_buckets<<<1, 1024, 0, stream>>>(bucketCount, bucketBase, bucketCursor);
    k_bin<<<NWG_BIN, TB, 0, stream>>>(row, col, bucketCursor, binned);
    k_bucket_deg<<<NB, TB, 0, stream>>>(binned, bucketBase, deg);
    k_block_sums<<<NSCAN, SCAN_THREADS, 0, stream>>>(deg, bsums);
    k_scan_bsums<<<1, 1024, 0, stream>>>(bsums, NSCAN);
    k_scan_final<<<NSCAN, SCAN_THREADS, 0, stream>>>(deg, bsums, ptr);
    k_bucket_scatter<<<NB, TB, 0, stream>>>(binned, bucketBase, ptr, sortedRow);
    k_dis<<<nodeGrid, TB, 0, stream>>>(deg, dis);

    k_lin1<<<nodeGrid, TB, 0, stream>>>(x, W1, dis, g1);
    k_pull<16, PAD><<<pullGrid, TB, 0, stream>>>(ptr, sortedRow, dis, g1, agg1);
    k_lin2<<<nodeGrid, TB, 0, stream>>>(agg1, b1, W2, dis);  // agg1 -> g2 in place
    k_pull<10, 10><<<pullGrid, TB, 0, stream>>>(ptr, sortedRow, dis, agg1, agg2);
    k_final<<<nodeGrid, TB, 0, stream>>>(agg2, b2, Wf, bf, out);
}